// Round 7
// baseline (194.845 us; speedup 1.0000x reference)
//
#include <hip/hip_runtime.h>
#include <stdint.h>

#define NHEADS 16
#define DHEAD 64
#define SEQ 2048
#define BATCH 2
#define NINF 1024
#define NOUTF 1024
#define N3 3072
#define MTOT 4096  // BATCH*SEQ

typedef unsigned short US;
typedef __attribute__((ext_vector_type(8))) short short8;
typedef __attribute__((ext_vector_type(4))) short short4v;
typedef __attribute__((ext_vector_type(4))) float f32x4;

__device__ inline US f2bf(float f) {
  union { float f; unsigned u; } v; v.f = f;
  unsigned r = v.u + 0x7fffu + ((v.u >> 16) & 1u);
  return (US)(r >> 16);
}

__device__ inline f32x4 mfma16(short8 a, short8 b, f32x4 c) {
  return __builtin_amdgcn_mfma_f32_16x16x32_bf16(a, b, c, 0, 0, 0);
}

__device__ inline f32x4 mfma16k16(short4v a, short4v b, f32x4 c) {
  return __builtin_amdgcn_mfma_f32_16x16x16bf16_1k(a, b, c, 0, 0, 0);
}

__device__ inline void async16(const US* g, US* l) {
  __builtin_amdgcn_global_load_lds(
      (const __attribute__((address_space(1))) unsigned int*)g,
      (__attribute__((address_space(3))) unsigned int*)l, 16, 0, 0);
}

// fp32 -> bf16, 4 elements/thread
__global__ void k_convert(const float* __restrict__ src, US* __restrict__ dst, int n4) {
  int i = blockIdx.x * blockDim.x + threadIdx.x;
  if (i >= n4) return;
  float4 v = ((const float4*)src)[i];
  ushort4 o;
  o.x = f2bf(v.x); o.y = f2bf(v.y); o.z = f2bf(v.z); o.w = f2bf(v.w);
  ((ushort4*)dst)[i] = o;
}

// merged weight transpose: Wqkv [1024][3072] and Wff [1024][1024] -> bf16 [C][1024]
__global__ void k_wtrans(const float* __restrict__ Wqkv, const float* __restrict__ Wff,
                         US* __restrict__ dq, US* __restrict__ df) {
  __shared__ float tile[32][33];
  int bxi = blockIdx.x;
  const float* src; US* dst; int C;
  if (bxi < 96) { src = Wqkv; dst = dq; C = N3; }
  else          { src = Wff;  dst = df; C = NOUTF; bxi -= 96; }
  int bx = bxi * 32, by = blockIdx.y * 32;
  int tx = threadIdx.x, ty = threadIdx.y;
  for (int i = 0; i < 32; i += 8)
    tile[ty + i][tx] = src[(size_t)(by + ty + i) * C + bx + tx];
  __syncthreads();
  for (int i = 0; i < 32; i += 8)
    dst[(size_t)(bx + ty + i) * 1024 + by + tx] = f2bf(tile[tx][ty + i]);
}

// per-bh bf16 transpose: vbuf [bh][2048][64] -> vtbuf [bh][64][2048]
__global__ void k_vtrans(const US* __restrict__ src, US* __restrict__ dst) {
  __shared__ US tile[32][33];
  int bh = blockIdx.z;
  int bx = blockIdx.x * 32;  // d
  int by = blockIdx.y * 32;  // s
  int tx = threadIdx.x, ty = threadIdx.y;
  const US* s0 = src + (size_t)bh * SEQ * DHEAD;
  US* d0 = dst + (size_t)bh * DHEAD * SEQ;
  for (int i = 0; i < 32; i += 8)
    tile[ty + i][tx] = s0[(size_t)(by + ty + i) * DHEAD + bx + tx];
  __syncthreads();
  for (int i = 0; i < 32; i += 8)
    d0[(size_t)(bx + ty + i) * SEQ + by + tx] = tile[tx][ty + i];
}

// ---------------- qkv GEMM: 128x128 tile, m97 structure ----------------
// Q is pre-scaled by log2(e)/sqrt(DHEAD) so attention scores are directly
// exp2 exponents.
__global__ __launch_bounds__(256) void k_gemm_qkv(
    const US* __restrict__ A,   // [MTOT][NINF]
    const US* __restrict__ Bt,  // [N3][NINF]
    US* __restrict__ qbuf, US* __restrict__ kbuf, US* __restrict__ vbuf) {
  __shared__ US As[128 * 32];
  __shared__ US Bs[128 * 32];
  int tid = threadIdx.x;
  int wave = tid >> 6, lane = tid & 63, lm = lane & 15, lk = lane >> 4;
  int wm = wave >> 1, wn = wave & 1;
  int mbase = blockIdx.y * 128, nbase = blockIdx.x * 128;

  f32x4 acc[4][4];
#pragma unroll
  for (int i = 0; i < 4; ++i)
#pragma unroll
    for (int j = 0; j < 4; ++j) acc[i][j] = (f32x4){0.f, 0.f, 0.f, 0.f};

  const US* ga = A + (size_t)(mbase + (tid >> 2)) * NINF + (tid & 3) * 8;
  const US* gb = Bt + (size_t)(nbase + (tid >> 2)) * NINF + (tid & 3) * 8;
  US* la = As + tid * 8;
  US* lb = Bs + tid * 8;

  for (int kt = 0; kt < NINF / 32; ++kt) {
    int ko = kt * 32;
    async16(ga + ko, la);
    async16(ga + ko + (size_t)64 * NINF, la + 64 * 32);
    async16(gb + ko, lb);
    async16(gb + ko + (size_t)64 * NINF, lb + 64 * 32);
    __syncthreads();
    short8 a[4], b[4];
#pragma unroll
    for (int i = 0; i < 4; ++i)
      a[i] = *(const short8*)(As + (wm * 64 + i * 16 + lm) * 32 + lk * 8);
#pragma unroll
    for (int j = 0; j < 4; ++j)
      b[j] = *(const short8*)(Bs + (wn * 64 + j * 16 + lm) * 32 + lk * 8);
#pragma unroll
    for (int i = 0; i < 4; ++i)
#pragma unroll
      for (int j = 0; j < 4; ++j) acc[i][j] = mfma16(a[i], b[j], acc[i][j]);
    __syncthreads();
  }

  int which = nbase >> 10;  // 0=q 1=k 2=v (uniform per block)
  US* dsts = (which == 0) ? qbuf : (which == 1) ? kbuf : vbuf;
  float sc = (which == 0) ? 0.18033688011112042f : 1.f;  // log2(e)/8 folded into Q
#pragma unroll
  for (int j = 0; j < 4; ++j) {
    int col = nbase + wn * 64 + j * 16 + lm;
    int hh = (col & 1023) >> 6;
    int d = col & 63;
#pragma unroll
    for (int i = 0; i < 4; ++i) {
#pragma unroll
      for (int r = 0; r < 4; ++r) {
        int row = mbase + wm * 64 + i * 16 + lk * 4 + r;
        int bb = row >> 11;
        int s = row & (SEQ - 1);
        int bh = bb * NHEADS + hh;
        dsts[((size_t)bh * SEQ + s) * DHEAD + d] = f2bf(acc[i][j][r] * sc);
      }
    }
  }
}

// ---------------- attention v7: paired strips + LDS double-buffer ----------------
// Block = 4 waves x 16 q-rows, processes strips (31-p) then (p): exactly 33
// 64-key tiles per block -> uniform work, 512 blocks, no tail.
// Double-buffered staging: stage tile t+1 AFTER the barrier, compute tile t,
// then one barrier per tile -> the vmcnt(0) drain at the barrier lands after
// compute has covered the staging latency (exposed stall ~0).
// S^T=K*Q^T -> P^T in C-layout == B-frag of mfma 16x16x16 -> PV from regs.
// Row-sums via ones-MFMA; P packed via +0x8000 bias + v_perm. (verified R5/R6)
__global__ __launch_bounds__(256) void k_attn(
    const US* __restrict__ qbuf, const US* __restrict__ kbuf,
    const US* __restrict__ vtbuf, US* __restrict__ ctx) {
  __shared__ US Ks[2][64 * 64];
  __shared__ US Vs[2][64 * 64];
  int tid = threadIdx.x;
  int w = tid >> 6, lane = tid & 63;
  int lm = lane & 15, lk = lane >> 4;
  int bl = blockIdx.x;
  int xcd = bl & 7, g = bl >> 3;
  int bh = (g & 3) * 8 + xcd;   // 4 bh per XCD -> working set ~3MB < 4MB L2
  int p = g >> 2;               // pair index 0..15

  const US* kbase = kbuf + (size_t)bh * SEQ * DHEAD;
  const US* vtb = vtbuf + (size_t)bh * DHEAD * SEQ;
  const US* q_base = qbuf + (size_t)bh * SEQ * DHEAD;
  US* cbase = ctx + (size_t)(bh >> 4) * SEQ * NOUTF + (bh & 15) * DHEAD;

  // staging geometry: 16 async16 units (8 K + 8 V), 4 per wave, XOR swizzle
  int swz = ((lane & 7) ^ (lane >> 3)) * 8;
  int u = w;                       // units w, w+4, w+8, w+12
  const US* gK0[2]; const US* gV0[2];
  US* dK[2][2]; US* dV[2][2];
#pragma unroll
  for (int j = 0; j < 2; ++j) {
    int uk = w + 4 * j;            // K units 0..7
    int uv = w + 4 * j;            // V units 0..7 (separate instr slots)
    gK0[j] = kbase + (size_t)(uk * 8 + (lane >> 3)) * DHEAD + swz;
    gV0[j] = vtb + (size_t)(uv * 8 + (lane >> 3)) * SEQ + swz;
#pragma unroll
    for (int b = 0; b < 2; ++b) {
      dK[b][j] = Ks[b] + uk * 512 + lane * 8;
      dV[b][j] = Vs[b] + uv * 512 + lane * 8;
    }
  }
  (void)u;

  // fragment-read offsets (bytes), swizzle-corrected
  int xorv = lm & 7;
  int ck0 = ((lk) ^ xorv) * 16;
  int ck1 = ((4 + lk) ^ xorv) * 16;
  const short4v kones = {(short)0x3F80, (short)0x3F80, (short)0x3F80, (short)0x3F80};

  for (int half = 0; half < 2; ++half) {
    int s = half ? p : (31 - p);
    int qb = s * 64 + w * 16;
    int nt = s + 1;

    const US* qr = q_base + (size_t)(qb + lm) * DHEAD + lk * 8;
    short8 qf0 = *(const short8*)(qr);
    short8 qf1 = *(const short8*)(qr + 32);

    f32x4 o[4];
#pragma unroll
    for (int dg = 0; dg < 4; ++dg) o[dg] = (f32x4){0.f, 0.f, 0.f, 0.f};
    f32x4 lacc = (f32x4){0.f, 0.f, 0.f, 0.f};

    const US* gK[2]; const US* gV[2];
#pragma unroll
    for (int j = 0; j < 2; ++j) { gK[j] = gK0[j]; gV[j] = gV0[j]; }

    // stage tile 0 -> buf 0
#pragma unroll
    for (int j = 0; j < 2; ++j) { async16(gK[j], dK[0][j]); async16(gV[j], dV[0][j]); }
#pragma unroll
    for (int j = 0; j < 2; ++j) { gK[j] += 64 * DHEAD; gV[j] += 64; }
    __syncthreads();  // buf0 ready

    for (int t = 0; t < nt; ++t) {
      int cur = t & 1, nxt = cur ^ 1;
      if (t + 1 < nt) {  // stage next tile now; compute below covers its latency
#pragma unroll
        for (int j = 0; j < 2; ++j) { async16(gK[j], dK[nxt][j]); async16(gV[j], dV[nxt][j]); }
#pragma unroll
        for (int j = 0; j < 2; ++j) { gK[j] += 64 * DHEAD; gV[j] += 64; }
      }

      const char* Kc = (const char*)Ks[cur];
      const char* Vc = (const char*)Vs[cur];
      auto body = [&](int kg, bool dm) {
        const char* kr = Kc + (kg * 16 + lm) * 128;
        short8 ka0 = *(const short8*)(kr + ck0);
        short8 ka1 = *(const short8*)(kr + ck1);
        f32x4 st = (f32x4){0.f, 0.f, 0.f, 0.f};
        st = mfma16(ka0, qf0, st);
        st = mfma16(ka1, qf1, st);
        uint32_t ue[4];
#pragma unroll
        for (int r = 0; r < 4; ++r) {
          float v = st[r];               // already log2-domain (Q pre-scaled)
          if (dm && (lk * 4 + r > lm)) v = -INFINITY;
          union { float f; uint32_t u; } cv2;
          cv2.f = exp2f(v);
          ue[r] = cv2.u + 0x8000u;       // bf16 bias-round; -inf -> +0
        }
        union { short4v s4; uint32_t u[2]; } pk;
        pk.u[0] = __builtin_amdgcn_perm(ue[1], ue[0], 0x07060302u);
        pk.u[1] = __builtin_amdgcn_perm(ue[3], ue[2], 0x07060302u);
        lacc = mfma16k16(kones, pk.s4, lacc);
        int cvo = (((kg * 2 + (lk >> 1)) ^ xorv) * 16) + (lk & 1) * 8;
        const char* vr = Vc + lm * 128 + cvo;
#pragma unroll
        for (int dg = 0; dg < 4; ++dg) {
          short4v va = *(const short4v*)(vr + dg * 2048);
          o[dg] = mfma16k16(va, pk.s4, o[dg]);
        }
      };

      if (t == nt - 1) {  // diagonal tile: kg > w fully masked
        for (int kg = 0; kg < w; ++kg) body(kg, false);
        body(w, true);
      } else {
#pragma unroll
        for (int kg = 0; kg < 4; ++kg) body(kg, false);
      }
      __syncthreads();  // cur reads done; nxt staging drained (covered by compute)
    }

    float inv = 1.f / lacc[0];
    US* crow = cbase + (size_t)(qb + lm) * NOUTF;
#pragma unroll
    for (int dg = 0; dg < 4; ++dg) {
      union { short4v s4; uint32_t u[2]; } pk;
      pk.u[0] = (uint32_t)f2bf(o[dg][0] * inv) | ((uint32_t)f2bf(o[dg][1] * inv) << 16);
      pk.u[1] = (uint32_t)f2bf(o[dg][2] * inv) | ((uint32_t)f2bf(o[dg][3] * inv) << 16);
      *(short4v*)(crow + dg * 16 + lk * 4) = pk.s4;
    }
  }
}

// ---------------- out GEMM: 128x64 tile, fused bias, fp32 out ------
__global__ __launch_bounds__(256) void k_gemm_out(
    const US* __restrict__ A, const US* __restrict__ Bt,
    const float* __restrict__ bias, float* __restrict__ out) {
  __shared__ US As[128 * 32];
  __shared__ US Bs[64 * 32];
  int tid = threadIdx.x;
  int wave = tid >> 6, lane = tid & 63, lm = lane & 15, lk = lane >> 4;
  int mbase = blockIdx.y * 128, nbase = blockIdx.x * 64;

  f32x4 acc[2][4];
#pragma unroll
  for (int i = 0; i < 2; ++i)
#pragma unroll
    for (int j = 0; j < 4; ++j) acc[i][j] = (f32x4){0.f, 0.f, 0.f, 0.f};

  const US* ga = A + (size_t)(mbase + (tid >> 2)) * NOUTF + (tid & 3) * 8;
  const US* gb = Bt + (size_t)(nbase + (tid >> 2)) * NOUTF + (tid & 3) * 8;
  US* la = As + tid * 8;
  US* lb = Bs + tid * 8;

  for (int kt = 0; kt < NOUTF / 32; ++kt) {
    int ko = kt * 32;
    async16(ga + ko, la);
    async16(ga + ko + (size_t)64 * NOUTF, la + 64 * 32);
    async16(gb + ko, lb);
    __syncthreads();
    short8 a[2], b[4];
#pragma unroll
    for (int i = 0; i < 2; ++i)
      a[i] = *(const short8*)(As + (wave * 32 + i * 16 + lm) * 32 + lk * 8);
#pragma unroll
    for (int j = 0; j < 4; ++j)
      b[j] = *(const short8*)(Bs + (j * 16 + lm) * 32 + lk * 8);
#pragma unroll
    for (int i = 0; i < 2; ++i)
#pragma unroll
      for (int j = 0; j < 4; ++j) acc[i][j] = mfma16(a[i], b[j], acc[i][j]);
    __syncthreads();
  }

#pragma unroll
  for (int j = 0; j < 4; ++j) {
    int col = nbase + j * 16 + lm;
    float bv = bias[col];
#pragma unroll
    for (int i = 0; i < 2; ++i)
#pragma unroll
      for (int r = 0; r < 4; ++r) {
        int row = mbase + wave * 32 + i * 16 + lk * 4 + r;
        out[(size_t)row * NOUTF + col] = acc[i][j][r] + bv;
      }
  }
}

extern "C" void kernel_launch(void* const* d_in, const int* in_sizes, int n_in,
                              void* d_out, int out_size, void* d_ws, size_t ws_size,
                              hipStream_t stream) {
  const float* y    = (const float*)d_in[0];
  const float* Wqkv = (const float*)d_in[1];
  const float* Wff  = (const float*)d_in[2];
  const float* bff  = (const float*)d_in[3];
  float* out = (float*)d_out;

  char* ws = (char*)d_ws;
  US* ybf   = (US*)(ws);                 // [0,8M)  y bf16; dead after qkv
  US* ctx   = (US*)(ws);                 // [0,8M)  reuse for ctx
  US* wqkvt = (US*)(ws + (8u << 20));    // [8,14M)
  US* wfft  = (US*)(ws + (14u << 20));   // [14,16M)
  US* qbuf  = (US*)(ws + (16u << 20));   // [16,24M)
  US* kbuf  = (US*)(ws + (24u << 20));   // [24,32M)
  US* vbuf  = (US*)(ws + (32u << 20));   // [32,40M) dead after vtrans
  US* vtbuf = (US*)(ws + (40u << 20));   // [40,48M)

  k_convert<<<MTOT * NINF / 4 / 256, 256, 0, stream>>>(y, ybf, MTOT * NINF / 4);
  k_wtrans<<<dim3(128, 32), dim3(32, 8), 0, stream>>>(Wqkv, Wff, wqkvt, wfft);
  k_gemm_qkv<<<dim3(N3 / 128, MTOT / 128), 256, 0, stream>>>(ybf, wqkvt, qbuf, kbuf, vbuf);
  k_vtrans<<<dim3(DHEAD / 32, SEQ / 32, BATCH * NHEADS), dim3(32, 8), 0, stream>>>(vbuf, vtbuf);
  k_attn<<<dim3(512), 256, 0, stream>>>(qbuf, kbuf, vtbuf, ctx);
  k_gemm_out<<<dim3(NOUTF / 64, MTOT / 128), 256, 0, stream>>>(ctx, wfft, bff, out);
}

// Round 8
// 194.096 us; speedup vs baseline: 1.0039x; 1.0039x over previous
//
#include <hip/hip_runtime.h>
#include <stdint.h>

#define NHEADS 16
#define DHEAD 64
#define SEQ 2048
#define BATCH 2
#define NINF 1024
#define NOUTF 1024
#define N3 3072
#define MTOT 4096  // BATCH*SEQ

typedef unsigned short US;
typedef __attribute__((ext_vector_type(8))) short short8;
typedef __attribute__((ext_vector_type(4))) short short4v;
typedef __attribute__((ext_vector_type(4))) float f32x4;

#if __has_builtin(__builtin_amdgcn_exp2f)
#define EXP2(x) __builtin_amdgcn_exp2f(x)
#else
#define EXP2(x) exp2f(x)
#endif

__device__ inline US f2bf(float f) {
  union { float f; unsigned u; } v; v.f = f;
  unsigned r = v.u + 0x7fffu + ((v.u >> 16) & 1u);
  return (US)(r >> 16);
}

__device__ inline f32x4 mfma16(short8 a, short8 b, f32x4 c) {
  return __builtin_amdgcn_mfma_f32_16x16x32_bf16(a, b, c, 0, 0, 0);
}

__device__ inline f32x4 mfma16k16(short4v a, short4v b, f32x4 c) {
  return __builtin_amdgcn_mfma_f32_16x16x16bf16_1k(a, b, c, 0, 0, 0);
}

__device__ inline void async16(const US* g, US* l) {
  __builtin_amdgcn_global_load_lds(
      (const __attribute__((address_space(1))) unsigned int*)g,
      (__attribute__((address_space(3))) unsigned int*)l, 16, 0, 0);
}

// fp32 -> bf16, 4 elements/thread
__global__ void k_convert(const float* __restrict__ src, US* __restrict__ dst, int n4) {
  int i = blockIdx.x * blockDim.x + threadIdx.x;
  if (i >= n4) return;
  float4 v = ((const float4*)src)[i];
  ushort4 o;
  o.x = f2bf(v.x); o.y = f2bf(v.y); o.z = f2bf(v.z); o.w = f2bf(v.w);
  ((ushort4*)dst)[i] = o;
}

// merged weight transpose: Wqkv [1024][3072] and Wff [1024][1024] -> bf16 [C][1024]
__global__ void k_wtrans(const float* __restrict__ Wqkv, const float* __restrict__ Wff,
                         US* __restrict__ dq, US* __restrict__ df) {
  __shared__ float tile[32][33];
  int bxi = blockIdx.x;
  const float* src; US* dst; int C;
  if (bxi < 96) { src = Wqkv; dst = dq; C = N3; }
  else          { src = Wff;  dst = df; C = NOUTF; bxi -= 96; }
  int bx = bxi * 32, by = blockIdx.y * 32;
  int tx = threadIdx.x, ty = threadIdx.y;
  for (int i = 0; i < 32; i += 8)
    tile[ty + i][tx] = src[(size_t)(by + ty + i) * C + bx + tx];
  __syncthreads();
  for (int i = 0; i < 32; i += 8)
    dst[(size_t)(bx + ty + i) * 1024 + by + tx] = f2bf(tile[tx][ty + i]);
}

// per-bh bf16 transpose: vbuf [bh][2048][64] -> vtbuf [bh][64][2048]
__global__ void k_vtrans(const US* __restrict__ src, US* __restrict__ dst) {
  __shared__ US tile[32][33];
  int bh = blockIdx.z;
  int bx = blockIdx.x * 32;  // d
  int by = blockIdx.y * 32;  // s
  int tx = threadIdx.x, ty = threadIdx.y;
  const US* s0 = src + (size_t)bh * SEQ * DHEAD;
  US* d0 = dst + (size_t)bh * DHEAD * SEQ;
  for (int i = 0; i < 32; i += 8)
    tile[ty + i][tx] = s0[(size_t)(by + ty + i) * DHEAD + bx + tx];
  __syncthreads();
  for (int i = 0; i < 32; i += 8)
    d0[(size_t)(bx + ty + i) * SEQ + by + tx] = tile[tx][ty + i];
}

// ---------------- qkv GEMM: 128x128 tile, m97 structure ----------------
// Q is pre-scaled by log2(e)/sqrt(DHEAD) so attention scores are directly
// exp2 exponents.
__global__ __launch_bounds__(256) void k_gemm_qkv(
    const US* __restrict__ A,   // [MTOT][NINF]
    const US* __restrict__ Bt,  // [N3][NINF]
    US* __restrict__ qbuf, US* __restrict__ kbuf, US* __restrict__ vbuf) {
  __shared__ US As[128 * 32];
  __shared__ US Bs[128 * 32];
  int tid = threadIdx.x;
  int wave = tid >> 6, lane = tid & 63, lm = lane & 15, lk = lane >> 4;
  int wm = wave >> 1, wn = wave & 1;
  int mbase = blockIdx.y * 128, nbase = blockIdx.x * 128;

  f32x4 acc[4][4];
#pragma unroll
  for (int i = 0; i < 4; ++i)
#pragma unroll
    for (int j = 0; j < 4; ++j) acc[i][j] = (f32x4){0.f, 0.f, 0.f, 0.f};

  const US* ga = A + (size_t)(mbase + (tid >> 2)) * NINF + (tid & 3) * 8;
  const US* gb = Bt + (size_t)(nbase + (tid >> 2)) * NINF + (tid & 3) * 8;
  US* la = As + tid * 8;
  US* lb = Bs + tid * 8;

  for (int kt = 0; kt < NINF / 32; ++kt) {
    int ko = kt * 32;
    async16(ga + ko, la);
    async16(ga + ko + (size_t)64 * NINF, la + 64 * 32);
    async16(gb + ko, lb);
    async16(gb + ko + (size_t)64 * NINF, lb + 64 * 32);
    __syncthreads();
    short8 a[4], b[4];
#pragma unroll
    for (int i = 0; i < 4; ++i)
      a[i] = *(const short8*)(As + (wm * 64 + i * 16 + lm) * 32 + lk * 8);
#pragma unroll
    for (int j = 0; j < 4; ++j)
      b[j] = *(const short8*)(Bs + (wn * 64 + j * 16 + lm) * 32 + lk * 8);
#pragma unroll
    for (int i = 0; i < 4; ++i)
#pragma unroll
      for (int j = 0; j < 4; ++j) acc[i][j] = mfma16(a[i], b[j], acc[i][j]);
    __syncthreads();
  }

  int which = nbase >> 10;  // 0=q 1=k 2=v (uniform per block)
  US* dsts = (which == 0) ? qbuf : (which == 1) ? kbuf : vbuf;
  float sc = (which == 0) ? 0.18033688011112042f : 1.f;  // log2(e)/8 folded into Q
#pragma unroll
  for (int j = 0; j < 4; ++j) {
    int col = nbase + wn * 64 + j * 16 + lm;
    int hh = (col & 1023) >> 6;
    int d = col & 63;
#pragma unroll
    for (int i = 0; i < 4; ++i) {
#pragma unroll
      for (int r = 0; r < 4; ++r) {
        int row = mbase + wm * 64 + i * 16 + lk * 4 + r;
        int bb = row >> 11;
        int s = row & (SEQ - 1);
        int bh = bb * NHEADS + hh;
        dsts[((size_t)bh * SEQ + s) * DHEAD + d] = f2bf(acc[i][j][r] * sc);
      }
    }
  }
}

// ---------------- attention v8: 32 q-rows/wave, v6 barrier structure ----------------
// Block = 2 waves x 32 q-rows = 64-row strip; 1024 blocks (4/CU), heavy-first,
// bh pinned to XCD. Single-buffered 64-key LDS tiles (K 8KB + V 8KB).
// Key change vs v6: 32 rows/wave -> K/V fragment LDS reads (16KB/tile/wave,
// independent of rows) amortize over 2x rows => LDS-read bytes halve.
// S^T=K*Q^T -> P^T in C-layout == B-frag of mfma 16x16x16 -> PV from regs.
// Row-sums via ones-MFMA; P packed via +0x8000 bias + v_perm; raw v_exp_f32.
__global__ __launch_bounds__(128, 2) void k_attn(
    const US* __restrict__ qbuf, const US* __restrict__ kbuf,
    const US* __restrict__ vtbuf, US* __restrict__ ctx) {
  __shared__ US Ks[64 * 64];
  __shared__ US Vs[64 * 64];
  int tid = threadIdx.x;
  int w = tid >> 6, lane = tid & 63;
  int lm = lane & 15, lk = lane >> 4;
  int bl = blockIdx.x;
  int xcd = bl & 7, g2 = bl >> 3;
  int bh = (g2 & 3) * 8 + xcd;   // 4 bh per XCD -> working set ~3MB < 4MB L2
  int s = 31 - (g2 >> 2);        // heaviest strip first
  int qb = s * 64 + w * 32;      // this wave's 32 rows
  int nt = s + 1;                // 64-key tiles

  const US* kbase = kbuf + (size_t)bh * SEQ * DHEAD;
  const US* vtb = vtbuf + (size_t)bh * DHEAD * SEQ;
  const US* q_base = qbuf + (size_t)bh * SEQ * DHEAD;

  // Q fragments for the wave's two 16-row groups
  short8 qf[2][2];
#pragma unroll
  for (int g = 0; g < 2; ++g) {
    const US* qr = q_base + (size_t)(qb + g * 16 + lm) * DHEAD + lk * 8;
    qf[g][0] = *(const short8*)(qr);
    qf[g][1] = *(const short8*)(qr + 32);
  }

  // staging: 16 async16 units (8 K + 8 V), 8 per wave, source-side XOR swizzle
  int swz = ((lane & 7) ^ (lane >> 3)) * 8;
  const US* gK[4]; const US* gV[4];
  US* dKl[4]; US* dVl[4];
#pragma unroll
  for (int j = 0; j < 4; ++j) {
    int u = w * 4 + j;  // units 0..7 per array
    gK[j] = kbase + (size_t)(u * 8 + (lane >> 3)) * DHEAD + swz;
    dKl[j] = Ks + u * 512 + lane * 8;
    gV[j] = vtb + (size_t)(u * 8 + (lane >> 3)) * SEQ + swz;
    dVl[j] = Vs + u * 512 + lane * 8;
  }

  // fragment-read offsets (bytes), swizzle-corrected
  int xorv = lm & 7;
  int ck0 = ((lk) ^ xorv) * 16;
  int ck1 = ((4 + lk) ^ xorv) * 16;
  const short4v kones = {(short)0x3F80, (short)0x3F80, (short)0x3F80, (short)0x3F80};

  f32x4 o[2][4];
#pragma unroll
  for (int g = 0; g < 2; ++g)
#pragma unroll
    for (int dg = 0; dg < 4; ++dg) o[g][dg] = (f32x4){0.f, 0.f, 0.f, 0.f};
  f32x4 lacc[2];
  lacc[0] = (f32x4){0.f, 0.f, 0.f, 0.f};
  lacc[1] = (f32x4){0.f, 0.f, 0.f, 0.f};

  const char* Kc = (const char*)Ks;
  const char* Vc = (const char*)Vs;

  // act/dm per row-group; act must imply pk[g] defined
  auto body = [&](int kg, bool act0, bool dm0, bool dm1) {
    const char* kr = Kc + (kg * 16 + lm) * 128;
    short8 ka0 = *(const short8*)(kr + ck0);
    short8 ka1 = *(const short8*)(kr + ck1);
    short4v pk[2];
    bool act[2] = {act0, true};
    bool dm[2] = {dm0, dm1};
#pragma unroll
    for (int g = 0; g < 2; ++g) {
      if (!act[g]) continue;
      f32x4 st = (f32x4){0.f, 0.f, 0.f, 0.f};
      st = mfma16(ka0, qf[g][0], st);
      st = mfma16(ka1, qf[g][1], st);
      uint32_t ue[4];
#pragma unroll
      for (int r = 0; r < 4; ++r) {
        float v = st[r];                  // already log2-domain (Q pre-scaled)
        if (dm[g] && (lk * 4 + r > lm)) v = -INFINITY;
        union { float f; uint32_t u; } cv2;
        cv2.f = EXP2(v);
        ue[r] = cv2.u + 0x8000u;          // bf16 bias-round; -inf -> +0
      }
      union { short4v s4; uint32_t u[2]; } pz;
      pz.u[0] = __builtin_amdgcn_perm(ue[1], ue[0], 0x07060302u);
      pz.u[1] = __builtin_amdgcn_perm(ue[3], ue[2], 0x07060302u);
      pk[g] = pz.s4;
      lacc[g] = mfma16k16(kones, pk[g], lacc[g]);
    }
    int cvo = (((kg * 2 + (lk >> 1)) ^ xorv) * 16) + (lk & 1) * 8;
    const char* vr = Vc + lm * 128 + cvo;
#pragma unroll
    for (int dg = 0; dg < 4; ++dg) {
      short4v va = *(const short4v*)(vr + dg * 2048);
      if (act0) o[0][dg] = mfma16k16(va, pk[0], o[0][dg]);
      o[1][dg] = mfma16k16(va, pk[1], o[1][dg]);
    }
  };

  for (int t = 0; t < nt; ++t) {
    __syncthreads();  // prior tile's LDS reads complete before overwrite
#pragma unroll
    for (int j = 0; j < 4; ++j) { async16(gK[j], dKl[j]); async16(gV[j], dVl[j]); }
#pragma unroll
    for (int j = 0; j < 4; ++j) { gK[j] += 64 * DHEAD; gV[j] += 64; }
    __syncthreads();  // staged data visible (vmcnt drained at barrier)

    if (t < nt - 1) {
#pragma unroll
      for (int kg = 0; kg < 4; ++kg) body(kg, true, false, false);
    } else {
      // diagonal tile: group g active iff kg <= 2w+g, diag iff kg == 2w+g
      int kmax = 2 * w + 1;
      for (int kg = 0; kg <= kmax; ++kg)
        body(kg, kg <= 2 * w, kg == 2 * w, kg == kmax);
    }
  }

  // outputs: row = qb + g*16 + lm, col = (bh&15)*64 + dg*16 + lk*4 + r
  US* cb = ctx + (size_t)(bh >> 4) * SEQ * NOUTF + (bh & 15) * DHEAD;
#pragma unroll
  for (int g = 0; g < 2; ++g) {
    float inv = 1.f / lacc[g][0];
    US* crow = cb + (size_t)(qb + g * 16 + lm) * NOUTF;
#pragma unroll
    for (int dg = 0; dg < 4; ++dg) {
      union { short4v s4; uint32_t u[2]; } pz;
      pz.u[0] = (uint32_t)f2bf(o[g][dg][0] * inv) | ((uint32_t)f2bf(o[g][dg][1] * inv) << 16);
      pz.u[1] = (uint32_t)f2bf(o[g][dg][2] * inv) | ((uint32_t)f2bf(o[g][dg][3] * inv) << 16);
      *(short4v*)(crow + dg * 16 + lk * 4) = pz.s4;
    }
  }
}

// ---------------- out GEMM: 128x64 tile, fused bias, fp32 out ------
__global__ __launch_bounds__(256) void k_gemm_out(
    const US* __restrict__ A, const US* __restrict__ Bt,
    const float* __restrict__ bias, float* __restrict__ out) {
  __shared__ US As[128 * 32];
  __shared__ US Bs[64 * 32];
  int tid = threadIdx.x;
  int wave = tid >> 6, lane = tid & 63, lm = lane & 15, lk = lane >> 4;
  int mbase = blockIdx.y * 128, nbase = blockIdx.x * 64;

  f32x4 acc[2][4];
#pragma unroll
  for (int i = 0; i < 2; ++i)
#pragma unroll
    for (int j = 0; j < 4; ++j) acc[i][j] = (f32x4){0.f, 0.f, 0.f, 0.f};

  const US* ga = A + (size_t)(mbase + (tid >> 2)) * NOUTF + (tid & 3) * 8;
  const US* gb = Bt + (size_t)(nbase + (tid >> 2)) * NOUTF + (tid & 3) * 8;
  US* la = As + tid * 8;
  US* lb = Bs + tid * 8;

  for (int kt = 0; kt < NOUTF / 32; ++kt) {
    int ko = kt * 32;
    async16(ga + ko, la);
    async16(ga + ko + (size_t)64 * NOUTF, la + 64 * 32);
    async16(gb + ko, lb);
    __syncthreads();
    short8 a[2], b[4];
#pragma unroll
    for (int i = 0; i < 2; ++i)
      a[i] = *(const short8*)(As + (wave * 32 + i * 16 + lm) * 32 + lk * 8);
#pragma unroll
    for (int j = 0; j < 4; ++j)
      b[j] = *(const short8*)(Bs + (j * 16 + lm) * 32 + lk * 8);
#pragma unroll
    for (int i = 0; i < 2; ++i)
#pragma unroll
      for (int j = 0; j < 4; ++j) acc[i][j] = mfma16(a[i], b[j], acc[i][j]);
    __syncthreads();
  }

#pragma unroll
  for (int j = 0; j < 4; ++j) {
    int col = nbase + j * 16 + lm;
    float bv = bias[col];
#pragma unroll
    for (int i = 0; i < 2; ++i)
#pragma unroll
      for (int r = 0; r < 4; ++r) {
        int row = mbase + wave * 32 + i * 16 + lk * 4 + r;
        out[(size_t)row * NOUTF + col] = acc[i][j][r] + bv;
      }
  }
}

extern "C" void kernel_launch(void* const* d_in, const int* in_sizes, int n_in,
                              void* d_out, int out_size, void* d_ws, size_t ws_size,
                              hipStream_t stream) {
  const float* y    = (const float*)d_in[0];
  const float* Wqkv = (const float*)d_in[1];
  const float* Wff  = (const float*)d_in[2];
  const float* bff  = (const float*)d_in[3];
  float* out = (float*)d_out;

  char* ws = (char*)d_ws;
  US* ybf   = (US*)(ws);                 // [0,8M)  y bf16; dead after qkv
  US* ctx   = (US*)(ws);                 // [0,8M)  reuse for ctx
  US* wqkvt = (US*)(ws + (8u << 20));    // [8,14M)
  US* wfft  = (US*)(ws + (14u << 20));   // [14,16M)
  US* qbuf  = (US*)(ws + (16u << 20));   // [16,24M)
  US* kbuf  = (US*)(ws + (24u << 20));   // [24,32M)
  US* vbuf  = (US*)(ws + (32u << 20));   // [32,40M) dead after vtrans
  US* vtbuf = (US*)(ws + (40u << 20));   // [40,48M)

  k_convert<<<MTOT * NINF / 4 / 256, 256, 0, stream>>>(y, ybf, MTOT * NINF / 4);
  k_wtrans<<<dim3(128, 32), dim3(32, 8), 0, stream>>>(Wqkv, Wff, wqkvt, wfft);
  k_gemm_qkv<<<dim3(N3 / 128, MTOT / 128), 256, 0, stream>>>(ybf, wqkvt, qbuf, kbuf, vbuf);
  k_vtrans<<<dim3(DHEAD / 32, SEQ / 32, BATCH * NHEADS), dim3(32, 8), 0, stream>>>(vbuf, vtbuf);
  k_attn<<<dim3(1024), 128, 0, stream>>>(qbuf, kbuf, vtbuf, ctx);
  k_gemm_out<<<dim3(NOUTF / 64, MTOT / 128), 256, 0, stream>>>(ctx, wfft, bff, out);
}